// Round 4
// baseline (26.010 us; speedup 1.0000x reference)
//
#include <hip/hip_runtime.h>

#define L 8192
#define ATT 1024
#define NPREV 8

__device__ inline float fast_tanh(float x) {
    // tanh(x) = 1 - 2/(exp(2x)+1); saturates correctly
    float e = __expf(2.0f * x);
    return 1.0f - 2.0f / (e + 1.0f);
}

// K1: b<1024: bd[b] = dot(dec_z, mlp_dec_w[b,:]) + mlp_dec_b[b] + wvec_b[b]
//     b>=1024 (32 blocks): cov[l] = sum_p att_prev[p][l]; copy old rows to out
__global__ __launch_bounds__(256) void k_prep(
    const float* __restrict__ dec_z, const float* __restrict__ mlp_dec_w,
    const float* __restrict__ mlp_dec_b, const float* __restrict__ wvec_b,
    const float* __restrict__ att_prev,
    float* __restrict__ bd, float* __restrict__ cov, float* __restrict__ out_att)
{
    int b = blockIdx.x, t = threadIdx.x;
    if (b < 1024) {
        __shared__ float red[4];
        int wave = t >> 6, lane = t & 63;
        const float4* wrow = (const float4*)(mlp_dec_w + (size_t)b * ATT);
        const float4* dz   = (const float4*)dec_z;
        float4 wv = wrow[t], zv = dz[t];
        float s = wv.x * zv.x + wv.y * zv.y + wv.z * zv.z + wv.w * zv.w;
        #pragma unroll
        for (int off = 32; off; off >>= 1) s += __shfl_down(s, off, 64);
        if (lane == 0) red[wave] = s;
        __syncthreads();
        if (t == 0) bd[b] = red[0] + red[1] + red[2] + red[3]
                            + mlp_dec_b[b] + wvec_b[b];
    } else {
        int l = (b - 1024) * 256 + t;
        float s = 0.f;
        #pragma unroll
        for (int p = 0; p < NPREV; ++p) {
            float v = att_prev[p * L + l];
            out_att[p * L + l] = v;
            s += v;
        }
        cov[l] = s;
    }
}

// K2: per-wave streaming. Each wave scores 2 rows (all lanes get the sum via
// xor-butterfly), computes unnormalized u in-register, and immediately
// accumulates the same rows' enc_h columns. One barrier pair at the end for
// the two-step cross-wave LDS combine.
template<int NWAVE>
__global__ __launch_bounds__(NWAVE * 64) void k_score_ctx(
    const float* __restrict__ pre_enc, const float* __restrict__ enc_h,
    const float* __restrict__ cov, const float* __restrict__ wvec_w,
    const float* __restrict__ bd, const float* __restrict__ gvec_w,
    const float* __restrict__ gvec_b, const float* __restrict__ mask,
    float* __restrict__ u_out,    // out_att row 8 (unnormalized)
    float* __restrict__ usum,     // per-block u sums
    float* __restrict__ partial)  // [NB][ATT]
{
    constexpr int RPB = NWAVE * 2;   // rows per block
    constexpr int HW  = NWAVE / 2;
    __shared__ float lds_acc[HW * 1024];
    __shared__ float uw[NWAVE];
    int t = threadIdx.x, b = blockIdx.x;
    int base = b * RPB;
    int wave = t >> 6, lane = t & 63;

    const float4* ww  = (const float4*)wvec_w;
    const float4* bdv = (const float4*)bd;
    const float4* gw  = (const float4*)gvec_w;
    float4 W4[4], BD4[4], G4[4];
    #pragma unroll
    for (int k = 0; k < 4; ++k) {
        W4[k]  = ww[lane + 64 * k];
        BD4[k] = bdv[lane + 64 * k];
        G4[k]  = gw[lane + 64 * k];
    }
    float gb = gvec_b[0];

    const float4* enc = (const float4*)enc_h;
    float4 acc[4] = {};
    float us_w = 0.f;

    #pragma unroll
    for (int rr = 0; rr < 2; ++rr) {
        int l = base + wave * 2 + rr;
        float cv = cov[l];
        const float4* row = (const float4*)(pre_enc + (size_t)l * ATT);
        float s = 0.f;
        #pragma unroll
        for (int k = 0; k < 4; ++k) {
            float4 pe = row[lane + 64 * k];
            s += fast_tanh(fmaf(cv, W4[k].x, BD4[k].x) + pe.x) * G4[k].x;
            s += fast_tanh(fmaf(cv, W4[k].y, BD4[k].y) + pe.y) * G4[k].y;
            s += fast_tanh(fmaf(cv, W4[k].z, BD4[k].z) + pe.z) * G4[k].z;
            s += fast_tanh(fmaf(cv, W4[k].w, BD4[k].w) + pe.w) * G4[k].w;
        }
        #pragma unroll
        for (int off = 32; off; off >>= 1) s += __shfl_xor(s, off, 64);
        // |2(s+gb+mask)| <= 2*sum|gw| ~ 33 -> exp safe in f32, no max pass
        float uv = __expf(2.0f * (s + gb + mask[l]));
        if (lane == 0) { u_out[l] = uv; us_w += uv; }
        #pragma unroll
        for (int k = 0; k < 4; ++k) {
            float4 v = enc[(size_t)l * 256 + k * 64 + lane];
            acc[k].x += uv * v.x; acc[k].y += uv * v.y;
            acc[k].z += uv * v.z; acc[k].w += uv * v.w;
        }
    }
    if (lane == 0) uw[wave] = us_w;

    // two-step combine: upper waves stage, lower waves add, then tree over HW
    float4* la = (float4*)lds_acc;
    if (wave >= HW) {
        #pragma unroll
        for (int k = 0; k < 4; ++k)
            la[(wave - HW) * 256 + k * 64 + lane] = acc[k];
    }
    __syncthreads();
    if (wave < HW) {
        #pragma unroll
        for (int k = 0; k < 4; ++k) {
            float4 o = la[wave * 256 + k * 64 + lane];
            o.x += acc[k].x; o.y += acc[k].y;
            o.z += acc[k].z; o.w += acc[k].w;
            la[wave * 256 + k * 64 + lane] = o;
        }
    }
    __syncthreads();
    constexpr int CPT = 1024 / (NWAVE * 64);
    #pragma unroll
    for (int cc = 0; cc < CPT; ++cc) {
        int col = t + cc * NWAVE * 64;
        float s = 0.f;
        #pragma unroll
        for (int w = 0; w < HW; ++w) s += lds_acc[w * 1024 + col];
        partial[(size_t)b * 1024 + col] = s;
    }
    if (t == 0) {
        float s = 0.f;
        #pragma unroll
        for (int w = 0; w < NWAVE; ++w) s += uw[w];
        usum[b] = s;
    }
}

// K3: blocks 0..63 -> c (reduce NB partial rows); 64..95 -> scale w in place
template<int NB>
__global__ __launch_bounds__(256) void k_finalize(
    const float* __restrict__ usum, const float* __restrict__ partial,
    float* __restrict__ out_c, float* __restrict__ w_inplace)
{
    __shared__ float red[4];
    __shared__ float s_inv_sh;
    __shared__ float4 wred[4][4];
    int t = threadIdx.x, b = blockIdx.x;
    int wave = t >> 6, lane = t & 63;

    float v = 0.f;
    for (int i = t; i < NB; i += 256) v += usum[i];
    #pragma unroll
    for (int off = 32; off; off >>= 1) v += __shfl_down(v, off, 64);
    if (lane == 0) red[wave] = v;
    __syncthreads();
    if (t == 0) s_inv_sh = 1.0f / (red[0] + red[1] + red[2] + red[3]);
    __syncthreads();
    float inv = s_inv_sh;

    if (b < 64) {
        int c = t & 3, r = t >> 2;
        const float4* p4 = (const float4*)partial;
        float4 a = {0.f, 0.f, 0.f, 0.f};
        #pragma unroll
        for (int i = 0; i < NB / 64; ++i) {
            float4 vv = p4[(size_t)(r + 64 * i) * 256 + b * 4 + c];
            a.x += vv.x; a.y += vv.y; a.z += vv.z; a.w += vv.w;
        }
        #pragma unroll
        for (int off = 4; off <= 32; off <<= 1) {
            a.x += __shfl_xor(a.x, off, 64);
            a.y += __shfl_xor(a.y, off, 64);
            a.z += __shfl_xor(a.z, off, 64);
            a.w += __shfl_xor(a.w, off, 64);
        }
        if (lane < 4) wred[wave][lane] = a;
        __syncthreads();
        if (t < 4) {
            float4 s0 = wred[0][t], s1 = wred[1][t],
                   s2 = wred[2][t], s3 = wred[3][t];
            float4 o;
            o.x = (s0.x + s1.x + s2.x + s3.x) * inv;
            o.y = (s0.y + s1.y + s2.y + s3.y) * inv;
            o.z = (s0.z + s1.z + s2.z + s3.z) * inv;
            o.w = (s0.w + s1.w + s2.w + s3.w) * inv;
            ((float4*)out_c)[b * 4 + t] = o;
        }
    } else {
        w_inplace[(b - 64) * 256 + t] *= inv;
    }
}

extern "C" void kernel_launch(void* const* d_in, const int* in_sizes, int n_in,
                              void* d_out, int out_size, void* d_ws, size_t ws_size,
                              hipStream_t stream) {
    const float* dec_z     = (const float*)d_in[0];
    const float* att_prev  = (const float*)d_in[1];
    const float* pre_enc   = (const float*)d_in[2];
    const float* enc_h     = (const float*)d_in[3];
    const float* mask      = (const float*)d_in[4];
    const float* wvec_w    = (const float*)d_in[5];
    const float* wvec_b    = (const float*)d_in[6];
    const float* mlp_dec_w = (const float*)d_in[7];
    const float* mlp_dec_b = (const float*)d_in[8];
    const float* gvec_w    = (const float*)d_in[9];
    const float* gvec_b    = (const float*)d_in[10];

    float* out     = (float*)d_out;
    float* out_c   = out;          // [1024]
    float* out_att = out + 1024;   // [9*8192]
    float* out_w   = out_att + 8 * L;

    float* ws      = (float*)d_ws;
    float* bd      = ws;                       // 1024
    float* cov     = ws + 1024;                // 8192
    float* usum    = ws + 1024 + 8192;         // up to 512
    float* partial = ws + 1024 + 8192 + 512;   // up to 512*1024

    k_prep<<<1056, 256, 0, stream>>>(dec_z, mlp_dec_w, mlp_dec_b, wvec_b,
                                     att_prev, bd, cov, out_att);

    size_t need512 = (size_t)(1024 + 8192 + 512 + 512 * 1024) * 4;
    if (ws_size >= need512) {
        // 512 blocks x 512 threads: 2 blocks/CU, tails overlap
        k_score_ctx<8><<<512, 512, 0, stream>>>(pre_enc, enc_h, cov, wvec_w,
                                                bd, gvec_w, gvec_b, mask,
                                                out_w, usum, partial);
        k_finalize<512><<<96, 256, 0, stream>>>(usum, partial, out_c, out_w);
    } else {
        // fallback within smaller workspace: 256 blocks x 1024 threads
        k_score_ctx<16><<<256, 1024, 0, stream>>>(pre_enc, enc_h, cov, wvec_w,
                                                  bd, gvec_w, gvec_b, mask,
                                                  out_w, usum, partial);
        k_finalize<256><<<96, 256, 0, stream>>>(usum, partial, out_c, out_w);
    }
}